// Round 8
// baseline (439.674 us; speedup 1.0000x reference)
//
#include <hip/hip_runtime.h>
#include <hip/hip_fp16.h>
#include <cstddef>
#include <cstdint>

// x (16,4096,256) fp32, kernels (512,256) fp32, out (16,4096,256) fp32
#define BSZ 16
#define PN  4096
#define DD  256
#define CC  512
#define TP  128
#define TC  128
#define NPT (PN / TP)    // 32 position tiles
#define NKC 8            // 8 K-chunks of 32
#define KSCALE 1024.0f   // kernel pre-scale: keeps fp16 splits normal-range
#define BAND 0.15f       // > 2*rigorous score-error bound (scaled units)

typedef _Float16 f16x8 __attribute__((ext_vector_type(8)));
typedef float    f32x4 __attribute__((ext_vector_type(4)));

struct Top2 { float v1, v2; int i1, i2; };

// larger value wins; tie -> smaller index (jnp.argmax first-occurrence)
__device__ __forceinline__ void t2_insert(Top2& t, float v, int i) {
  if (v > t.v1 || (v == t.v1 && i < t.i1)) {
    t.v2 = t.v1; t.i2 = t.i1; t.v1 = v; t.i1 = i;
  } else if (v > t.v2 || (v == t.v2 && i < t.i2)) {
    t.v2 = v; t.i2 = i;
  }
}

// 8 fp32 -> 8 fp16 (RTN)
__device__ __forceinline__ f16x8 cvt8(float4 a, float4 b) {
  f16x8 r;
  r[0] = (_Float16)a.x; r[1] = (_Float16)a.y;
  r[2] = (_Float16)a.z; r[3] = (_Float16)a.w;
  r[4] = (_Float16)b.x; r[5] = (_Float16)b.y;
  r[6] = (_Float16)b.z; r[7] = (_Float16)b.w;
  return r;
}

// async 16B global -> LDS (dest = wave-uniform base + lane*16)
__device__ __forceinline__ void gld16(const void* gsrc, void* ldst) {
  __builtin_amdgcn_global_load_lds(
      (const __attribute__((address_space(1))) unsigned int*)gsrc,
      (__attribute__((address_space(3))) unsigned int*)ldst, 16, 0, 0);
}

// full-wave fp64 dot of one x row with one kernel row (all lanes get sum)
__device__ __forceinline__ double dot64(const float* __restrict__ xr,
                                        const float* __restrict__ kr, int lane) {
  int o = lane * 4;
  double s = (double)xr[o] * (double)kr[o]
           + (double)xr[o + 1] * (double)kr[o + 1]
           + (double)xr[o + 2] * (double)kr[o + 2]
           + (double)xr[o + 3] * (double)kr[o + 3];
#pragma unroll
  for (int m = 1; m < 64; m <<= 1) s += __shfl_xor(s, m, 64);
  return s;
}

// ---------------------------------------------------------------------------
// kernels (512x256) -> fp16 hi/lo (scaled by KSCALE) in MFMA slot order.
// Chunk (ct,kc) = 16 KB: hi[512 slots*16B] | lo[8KB offset]; slot
// s = fp*64 + kg*16 + lr holds channel row fp*16+lr, k = kc*32+kg*8..+8.
// Also zeroes the score tail counters (runs before score in-stream).
// ---------------------------------------------------------------------------
__global__ __launch_bounds__(256) void convert_k_kernel(
    const float* __restrict__ kern, uint32_t* __restrict__ ks,
    int* __restrict__ cnt) {
  const int kc = blockIdx.x, ct = blockIdx.y;
  if (kc == 0 && ct == 0 && threadIdx.x < 64) cnt[threadIdx.x] = 0;
  const size_t chunk = ((size_t)ct * NKC + kc) * 4096;
#pragma unroll
  for (int s0 = 0; s0 < 2; s0++) {
    int s  = threadIdx.x + s0 * 256;
    int fp = s >> 6, kg = (s >> 4) & 3, lr = s & 15;
    int r  = fp * 16 + lr, k0 = kg * 8;
    const float* src = kern + ((size_t)ct * TC + r) * DD + kc * 32 + k0;
    float4 v0 = *(const float4*)src, v1 = *(const float4*)(src + 4);
    float sv[8] = {v0.x, v0.y, v0.z, v0.w, v1.x, v1.y, v1.z, v1.w};
    f16x8 hi, lo;
#pragma unroll
    for (int i = 0; i < 8; i++) {
      float sc = sv[i] * KSCALE;
      _Float16 h = (_Float16)sc;
      hi[i] = h;
      lo[i] = (_Float16)(sc - (float)h);
    }
    *(uint4*)&ks[chunk + (size_t)s * 4]        = *(uint4*)&hi;
    *(uint4*)&ks[chunk + 2048 + (size_t)s * 4] = *(uint4*)&lo;
  }
}

// ---------------------------------------------------------------------------
// Score GEMM: 128p x 128c per block, fp16 2-term (xh*kh + xh*kl), fused
// per-column top-2, and fused final per-(b,c) reduction + fp64 rescue done
// by the last-arriving block of each (b,ct) group.
// A staged as raw fp32 via gld16 (permuted slots, h-bit above lane bits so
// frag reads are 16B-stride conflict-free), converted to fp16 in-register.
// ---------------------------------------------------------------------------
__global__ __launch_bounds__(256) void score_kernel(
    const float* __restrict__ x, const uint32_t* __restrict__ ks,
    const float* __restrict__ kern,
    float2* __restrict__ pv2, uint32_t* __restrict__ pix,
    int* __restrict__ win, int* __restrict__ cnt) {

  __shared__ __align__(16) char lds[32768];   // A fp32 [0,16K) | B f16 hi/lo [16K,32K)
  __shared__ int lastflag, nf;
  __shared__ short flist[TC];

  const int ct = blockIdx.x, pt = blockIdx.y, b = blockIdx.z;
  const int tid  = threadIdx.x;
  const int lane = tid & 63, wave = tid >> 6;
  const int wr = wave >> 1, wc = wave & 1;
  const int lr = lane & 15, kg = lane >> 4;

  // A slot s = [swr:1][sfp:2][sh:1][lane:6], LDS byte = s*16.
  // global: row = swr*64+sfp*16+(lane&15); bytes kc*128 + (lane>>4)*32 + sh*16
  const char* xbase = (const char*)x + ((size_t)b * PN + (size_t)pt * TP) * (DD * 4);
  const char* asrc[4];
#pragma unroll
  for (int i = 0; i < 4; i++) {
    int s = i * 256 + tid;
    int swr = s >> 9, sfp = (s >> 7) & 3, sh = (s >> 6) & 1, sl = s & 63;
    int row = swr * 64 + sfp * 16 + (sl & 15);
    asrc[i] = xbase + (size_t)row * (DD * 4) + (sl >> 4) * 32 + sh * 16;
  }
  const char* bsrc = (const char*)ks + ((size_t)ct * NKC) * 16384 + tid * 16;

  f32x4 acc[4][4];
#pragma unroll
  for (int i = 0; i < 4; i++)
#pragma unroll
    for (int j = 0; j < 4; j++) acc[i][j] = (f32x4)0.f;

  for (int kc = 0; kc < NKC; kc++) {
#pragma unroll
    for (int i = 0; i < 4; i++)
      gld16(asrc[i] + kc * 128, lds + i * 4096 + tid * 16);
#pragma unroll
    for (int i = 0; i < 4; i++)
      gld16(bsrc + kc * 16384 + i * 4096, lds + 16384 + i * 4096 + tid * 16);
    __syncthreads();   // drains vmcnt -> staged data visible

    f16x8 Ah[4];
#pragma unroll
    for (int fp = 0; fp < 4; fp++) {
      const char* apb = lds + wr * 8192 + fp * 2048 + lane * 16;
      float4 r0 = *(const float4*)apb;            // k = kg*8+0..3
      float4 r1 = *(const float4*)(apb + 1024);   // k = kg*8+4..7
      Ah[fp] = cvt8(r0, r1);
    }
#pragma unroll
    for (int fc = 0; fc < 4; fc++) {
      const char* bp = lds + 16384 + wc * 4096 + fc * 1024 + lane * 16;
      f16x8 Bh = *(const f16x8*)bp;
      f16x8 Bl = *(const f16x8*)(bp + 8192);
#pragma unroll
      for (int fp = 0; fp < 4; fp++) {
        acc[fp][fc] = __builtin_amdgcn_mfma_f32_16x16x32_f16(Ah[fp], Bh, acc[fp][fc], 0, 0, 0);
        acc[fp][fc] = __builtin_amdgcn_mfma_f32_16x16x32_f16(Ah[fp], Bl, acc[fp][fc], 0, 0, 0);
      }
    }
    __syncthreads();   // frag reads done before next chunk overwrites LDS
  }

  // relu + per-lane top2 per column (C layout: col=lane&15, row=kg*4+reg)
  float4* scratch = (float4*)lds;   // reuse tile LDS: [slot 0..7][col 0..127]
  const int slot = wr * 4 + kg;
#pragma unroll
  for (int fc = 0; fc < 4; fc++) {
    Top2 t; t.v1 = -1.f; t.v2 = -1.f; t.i1 = 0x7fffffff; t.i2 = 0x7fffffff;
#pragma unroll
    for (int fp = 0; fp < 4; fp++)
#pragma unroll
      for (int r = 0; r < 4; r++) {
        float v = acc[fp][fc][r]; v = v > 0.f ? v : 0.f;
        t2_insert(t, v, wr * 64 + fp * 16 + kg * 4 + r);
      }
    int c_local = wc * 64 + fc * 16 + lr;
    scratch[slot * TC + c_local] =
        make_float4(t.v1, __int_as_float(t.i1), t.v2, __int_as_float(t.i2));
  }
  __syncthreads();

  if (tid < TC) {
    Top2 t; t.v1 = -1.f; t.v2 = -1.f; t.i1 = 0x7fffffff; t.i2 = 0x7fffffff;
#pragma unroll
    for (int s = 0; s < 8; s++) {
      float4 e = scratch[s * TC + tid];
      t2_insert(t, e.x, __float_as_int(e.y));
      t2_insert(t, e.z, __float_as_int(e.w));
    }
    int c = ct * TC + tid;
    size_t o = ((size_t)b * CC + c) * NPT + pt;
    uint32_t p1 = (uint32_t)(pt * TP + t.i1);
    uint32_t p2 = (uint32_t)(pt * TP + t.i2);
    pv2[o] = make_float2(t.v1, t.v2);
    pix[o] = (p1 << 16) | (p2 & 0xffffu);
  }

  // ---- fused tail: last block of this (b,ct) group reduces 128 channels
  __threadfence();
  if (tid == 0) lastflag = (atomicAdd(&cnt[b * 4 + ct], 1) == NPT - 1);
  __syncthreads();
  if (!lastflag) return;
  __threadfence();
  if (tid == 0) nf = 0;
  __syncthreads();

  if (tid < TC) {
    int c = ct * TC + tid;
    size_t base = ((size_t)b * CC + c) * NPT;
    Top2 g; g.v1 = -1.f; g.v2 = -1.f; g.i1 = 0x7fffffff; g.i2 = 0x7fffffff;
    for (int i = 0; i < NPT; i++) {
      float2 v = pv2[base + i]; uint32_t ii = pix[base + i];
      t2_insert(g, v.x, (int)(ii >> 16));
      t2_insert(g, v.y, (int)(ii & 0xffffu));
    }
    if (g.v1 - g.v2 > BAND) {
      win[b * CC + c] = g.i1;          // certain winner
    } else {
      int idx = atomicAdd(&nf, 1);     // rare: needs exact rescue
      flist[idx] = (short)tid;
    }
  }
  __syncthreads();

  // rescue flagged channels: exact fp64 dots over the certified candidate set
  for (int f = wave; f < nf; f += 4) {
    int c = ct * TC + flist[f];
    size_t base = ((size_t)b * CC + c) * NPT;
    float v1t = -1.f, v2t = -1.f; int i1t = 0, i2t = 0;
    if (lane < NPT) {
      float2 v = pv2[base + lane]; uint32_t ii = pix[base + lane];
      v1t = v.x; v2t = v.y; i1t = (int)(ii >> 16); i2t = (int)(ii & 0xffffu);
    }
    float gv = v1t;
#pragma unroll
    for (int m = 1; m < 64; m <<= 1) gv = fmaxf(gv, __shfl_xor(gv, m, 64));
    float thr = gv - BAND;
    unsigned long long m1 = __ballot(lane < NPT && v1t >= thr);
    unsigned long long m2 = __ballot(lane < NPT && v2t >= thr);

    const float* xb = x + (size_t)b * PN * DD;
    const float* kr = kern + (size_t)c * DD;
    double bv = 0.0; int bp_ = 0;   // ties at <=0 resolve to argmax 0 (all-relu-0)

    unsigned long long mm = m1;
    while (mm) {
      int sl_ = __ffsll((long long)mm) - 1; mm &= mm - 1;
      int p = __shfl(i1t, sl_, 64);
      double s = dot64(xb + (size_t)p * DD, kr, lane);
      if (s > bv || (s == bv && p < bp_)) { bv = s; bp_ = p; }
    }
    mm = m2;
    while (mm) {
      int sl_ = __ffsll((long long)mm) - 1; mm &= mm - 1;
      int p = __shfl(i2t, sl_, 64);
      double s = dot64(xb + (size_t)p * DD, kr, lane);
      if (s > bv || (s == bv && p < bp_)) { bv = s; bp_ = p; }
    }
    // deep tiles (tile_v2 >= thr): 3rd-best could hide -> scan whole tile
    mm = m2;
    while (mm) {
      int tl = __ffsll((long long)mm) - 1; mm &= mm - 1;
      const float* xA = xb + (size_t)(tl * TP + lane) * DD;
      const float* xB = xA + (size_t)64 * DD;
      double sA = 0.0, sB = 0.0;
      for (int i = 0; i < DD; i++) {
        double kv = (double)kr[i];
        sA += (double)xA[i] * kv;
        sB += (double)xB[i] * kv;
      }
      double lv = sA; int lp = tl * TP + lane;
      if (sB > lv) { lv = sB; lp = tl * TP + lane + 64; }
#pragma unroll
      for (int m = 1; m < 64; m <<= 1) {
        double ov = __shfl_xor(lv, m, 64);
        int    op = __shfl_xor(lp, m, 64);
        if (ov > lv || (ov == lv && op < lp)) { lv = ov; lp = op; }
      }
      if (lv > bv || (lv == bv && lp < bp_)) { bv = lv; bp_ = lp; }
    }
    if (bv <= 0.0) bp_ = 0;          // entire column relu'd to 0 -> argmax 0
    if (lane == 0) win[b * CC + c] = bp_;
  }
}

// ---------------------------------------------------------------------------
// 16 positions per block (4 waves x 4); winner row staged in LDS once.
// Ascending-channel add order (matches reference scatter-add order).
// Full coverage -> no memset, no atomics.
// ---------------------------------------------------------------------------
__global__ __launch_bounds__(256) void write_out_kernel(
    const int* __restrict__ winner, const float* __restrict__ kern,
    float4* __restrict__ out) {
  __shared__ __align__(16) int wrow[CC];
  const int b = blockIdx.y;
  const int tid = threadIdx.x, lane = tid & 63, w = tid >> 6;

  *(int2*)&wrow[tid * 2] = *(const int2*)&winner[(size_t)b * CC + tid * 2];
  __syncthreads();

  int wv[8];
#pragma unroll
  for (int j = 0; j < 8; j++) wv[j] = wrow[j * 64 + lane];

#pragma unroll
  for (int pi = 0; pi < 4; pi++) {
    const int p = blockIdx.x * 16 + w * 4 + pi;
    float4 acc = make_float4(0.f, 0.f, 0.f, 0.f);
#pragma unroll
    for (int j = 0; j < 8; j++) {                 // j major: c ascending
      unsigned long long m = __ballot(wv[j] == p);
      while (m) {
        int bit = __ffsll((long long)m) - 1; m &= m - 1;
        int c = j * 64 + bit;                     // wave-uniform, ascending
        float4 kv = ((const float4*)(kern + (size_t)c * DD))[lane];
        acc.x += kv.x; acc.y += kv.y; acc.z += kv.z; acc.w += kv.w;
      }
    }
    out[((size_t)b * PN + p) * 64 + lane] = acc;
  }
}

// ---------------------------------------------------------------------------
extern "C" void kernel_launch(void* const* d_in, const int* in_sizes, int n_in,
                              void* d_out, int out_size, void* d_ws, size_t ws_size,
                              hipStream_t stream) {
  const float* x    = (const float*)d_in[0];   // (16,4096,256)
  const float* kern = (const float*)d_in[1];   // (512,256)
  float* out = (float*)d_out;

  // ws: pv2 2 MB | pix 1 MB | ks 512 KB | win 32 KB | cnt 256 B
  char* ws = (char*)d_ws;
  float2*   pv2 = (float2*)ws;
  uint32_t* pix = (uint32_t*)(ws + (size_t)BSZ * CC * NPT * sizeof(float2));
  uint32_t* ks  = (uint32_t*)(ws + 3u * 1024 * 1024);
  int*      win = (int*)(ws + 3u * 1024 * 1024 + 512u * 1024);
  int*      cnt = (int*)(ws + 3u * 1024 * 1024 + 512u * 1024 + 32u * 1024);

  convert_k_kernel<<<dim3(NKC, CC / TC), 256, 0, stream>>>(kern, ks, cnt);

  score_kernel<<<dim3(CC / TC, NPT, BSZ), 256, 0, stream>>>(
      x, ks, kern, pv2, pix, win, cnt);

  write_out_kernel<<<dim3(PN / 16, BSZ), 256, 0, stream>>>(win, kern, (float4*)out);
}

// Round 9
// 224.237 us; speedup vs baseline: 1.9608x; 1.9608x over previous
//
#include <hip/hip_runtime.h>
#include <hip/hip_fp16.h>
#include <cstddef>
#include <cstdint>

// x (16,4096,256) fp32, kernels (512,256) fp32, out (16,4096,256) fp32
#define BSZ 16
#define PN  4096
#define DD  256
#define CC  512
#define TP  128
#define TC  128
#define NPT (PN / TP)    // 32 position tiles
#define NKC 8            // 8 K-chunks of 32
#define KSCALE 1024.0f   // kernel pre-scale keeps fp16 splits normal-range
#define BAND 0.30f       // > 2 * rigorous score-error bound (scaled units)

typedef _Float16 f16x8 __attribute__((ext_vector_type(8)));
typedef float    f32x4 __attribute__((ext_vector_type(4)));

#define MEMFENCE() __asm__ __volatile__("" ::: "memory")
#define WAITCNT_VM0 0x1F70   // s_waitcnt vmcnt(0), lgkm/exp don't-care

struct Top2 { float v1, v2; int i1, i2; };

// larger value wins; tie -> smaller index (jnp.argmax first-occurrence)
__device__ __forceinline__ void t2_insert(Top2& t, float v, int i) {
  if (v > t.v1 || (v == t.v1 && i < t.i1)) {
    t.v2 = t.v1; t.i2 = t.i1; t.v1 = v; t.i1 = i;
  } else if (v > t.v2 || (v == t.v2 && i < t.i2)) {
    t.v2 = v; t.i2 = i;
  }
}

// 8 fp32 -> 8 fp16 (RTN)
__device__ __forceinline__ f16x8 cvt8(float4 a, float4 b) {
  f16x8 r;
  r[0] = (_Float16)a.x; r[1] = (_Float16)a.y;
  r[2] = (_Float16)a.z; r[3] = (_Float16)a.w;
  r[4] = (_Float16)b.x; r[5] = (_Float16)b.y;
  r[6] = (_Float16)b.z; r[7] = (_Float16)b.w;
  return r;
}

// async 16B global -> LDS (dest = wave-uniform base + lane*16)
__device__ __forceinline__ void gld16(const void* gsrc, void* ldst) {
  __builtin_amdgcn_global_load_lds(
      (const __attribute__((address_space(1))) unsigned int*)gsrc,
      (__attribute__((address_space(3))) unsigned int*)ldst, 16, 0, 0);
}

// full-wave fp64 dot of one x row with one kernel row (all lanes get sum)
__device__ __forceinline__ double dot64(const float* __restrict__ xr,
                                        const float* __restrict__ kr, int lane) {
  int o = lane * 4;
  double s = (double)xr[o] * (double)kr[o]
           + (double)xr[o + 1] * (double)kr[o + 1]
           + (double)xr[o + 2] * (double)kr[o + 2]
           + (double)xr[o + 3] * (double)kr[o + 3];
#pragma unroll
  for (int m = 1; m < 64; m <<= 1) s += __shfl_xor(s, m, 64);
  return s;
}

// ---------------------------------------------------------------------------
// Prep (one dispatch, 544 blocks):
//   blocks 0..511  : x -> fp16 (RTN) in A-slot order -> xh (in d_out, 33.5 MB)
//                    chunk (b,pt,kc) = 8 KB, slot s = wr*256+fp*64+kg*16+lr
//                    holds row wr*64+fp*16+lr, k = kc*32+kg*8..+8.
//   blocks 512..543: kernels*KSCALE -> fp16 hi/lo in B-slot order -> ks
//                    chunk (ct,kc) = 16 KB [hi 8K | lo 8K], slot s2 =
//                    wc*256+fc*64+kg*16+lr -> row ct*128+wc*64+fc*16+lr.
//   block 512 also zeroes the tail counters.
// ---------------------------------------------------------------------------
__global__ __launch_bounds__(256) void prep_kernel(
    const float* __restrict__ x, const float* __restrict__ kern,
    uint32_t* __restrict__ xh, uint32_t* __restrict__ ks,
    int* __restrict__ cnt) {
  const int bid = blockIdx.x, tid = threadIdx.x;
  if (bid < 512) {
    const int b = bid >> 5, pt = bid & 31;
    const int r = tid >> 1, hh = tid & 1;
    const int wr = r >> 6, fp = (r >> 4) & 3, lr = r & 15;
    const float* src = x + ((size_t)(b * PN + pt * TP + r)) * DD + hh * 128;
    const size_t chunk0 = ((size_t)(b * NPT + pt) * NKC) * 2048;   // u32 units
#pragma unroll
    for (int g = 0; g < 16; g++) {
      int kc = hh * 4 + (g >> 2), kg = g & 3;
      float4 v0 = *(const float4*)(src + g * 8);
      float4 v1 = *(const float4*)(src + g * 8 + 4);
      f16x8 h = cvt8(v0, v1);
      int slot = wr * 256 + fp * 64 + kg * 16 + lr;
      *(uint4*)&xh[chunk0 + (size_t)kc * 2048 + (size_t)slot * 4] = *(uint4*)&h;
    }
  } else {
    const int kk = bid - 512;
    const int ct = kk >> 3, kc = kk & 7;
    if (kk == 0 && tid < 64) cnt[tid] = 0;
    const size_t chunk = ((size_t)(ct * NKC + kc)) * 4096;          // u32 units
#pragma unroll
    for (int s0 = 0; s0 < 2; s0++) {
      int s2 = tid + s0 * 256;
      int wc = s2 >> 8, fc = (s2 >> 6) & 3, kg = (s2 >> 4) & 3, lr = s2 & 15;
      int row = ct * TC + wc * 64 + fc * 16 + lr;
      const float* src = kern + (size_t)row * DD + kc * 32 + kg * 8;
      float4 v0 = *(const float4*)src, v1 = *(const float4*)(src + 4);
      float sv[8] = {v0.x, v0.y, v0.z, v0.w, v1.x, v1.y, v1.z, v1.w};
      f16x8 hi, lo;
#pragma unroll
      for (int i = 0; i < 8; i++) {
        float sc = sv[i] * KSCALE;
        _Float16 h = (_Float16)sc;
        hi[i] = h;
        lo[i] = (_Float16)(sc - (float)h);
      }
      *(uint4*)&ks[chunk + (size_t)s2 * 4]        = *(uint4*)&hi;
      *(uint4*)&ks[chunk + 2048 + (size_t)s2 * 4] = *(uint4*)&lo;
    }
  }
}

// ---------------------------------------------------------------------------
// Score GEMM: 128p x 128c per block, fp16 2-term (xh*kh + xh*kl), fused
// per-column top-2, and fused final reduction + fp64 rescue by the last
// block of each (b,ct) group. Contiguous gld16 staging (24 KB/chunk).
// Handshake uses agent-scope (sc1) atomic stores/loads — NO threadfence.
// ---------------------------------------------------------------------------
__global__ __launch_bounds__(256) void score_kernel(
    const uint32_t* __restrict__ xh, const uint32_t* __restrict__ ks,
    const float* __restrict__ x, const float* __restrict__ kern,
    uint32_t* __restrict__ pw, int* __restrict__ win, int* __restrict__ cnt) {

  __shared__ __align__(16) char lds[24576];   // A f16 [0,8K) | B hi [8K,16K) | B lo [16K,24K)
  __shared__ int lastflag, nf;
  __shared__ short flist[TC];

  const int ct = blockIdx.x, pt = blockIdx.y, b = blockIdx.z;
  const int tid  = threadIdx.x;
  const int lane = tid & 63, wave = tid >> 6;
  const int wr = wave >> 1, wc = wave & 1;
  const int lr = lane & 15, kg = lane >> 4;

  const char* asrc = (const char*)xh + ((size_t)(b * NPT + pt) * NKC) * 8192 + tid * 16;
  const char* bsrc = (const char*)ks + ((size_t)ct * NKC) * 16384 + tid * 16;

  f32x4 acc[4][4];
#pragma unroll
  for (int i = 0; i < 4; i++)
#pragma unroll
    for (int j = 0; j < 4; j++) acc[i][j] = (f32x4)0.f;

  for (int kc = 0; kc < NKC; kc++) {
#pragma unroll
    for (int i = 0; i < 2; i++)
      gld16(asrc + kc * 8192 + i * 4096, lds + i * 4096 + tid * 16);
#pragma unroll
    for (int i = 0; i < 4; i++)
      gld16(bsrc + kc * 16384 + i * 4096, lds + 8192 + i * 4096 + tid * 16);
    __syncthreads();   // drains vmcnt -> staged data visible

    f16x8 Ah[4];
#pragma unroll
    for (int fp = 0; fp < 4; fp++)
      Ah[fp] = *(const f16x8*)(lds + wr * 4096 + fp * 1024 + lane * 16);
#pragma unroll
    for (int fc = 0; fc < 4; fc++) {
      const char* bp = lds + 8192 + wc * 4096 + fc * 1024 + lane * 16;
      f16x8 Bh = *(const f16x8*)bp;
      f16x8 Bl = *(const f16x8*)(bp + 8192);
#pragma unroll
      for (int fp = 0; fp < 4; fp++) {
        acc[fp][fc] = __builtin_amdgcn_mfma_f32_16x16x32_f16(Ah[fp], Bh, acc[fp][fc], 0, 0, 0);
        acc[fp][fc] = __builtin_amdgcn_mfma_f32_16x16x32_f16(Ah[fp], Bl, acc[fp][fc], 0, 0, 0);
      }
    }
    __syncthreads();   // frag reads done before next chunk overwrites LDS
  }

  // relu + per-lane top2 per column (C layout: col=lane&15, row=kg*4+reg)
  float4* scratch = (float4*)lds;   // reuse tile LDS: [slot 0..7][col 0..127]
  const int slot = wr * 4 + kg;
#pragma unroll
  for (int fc = 0; fc < 4; fc++) {
    Top2 t; t.v1 = -1.f; t.v2 = -1.f; t.i1 = 0x7fffffff; t.i2 = 0x7fffffff;
#pragma unroll
    for (int fp = 0; fp < 4; fp++)
#pragma unroll
      for (int r = 0; r < 4; r++) {
        float v = acc[fp][fc][r]; v = v > 0.f ? v : 0.f;
        t2_insert(t, v, wr * 64 + fp * 16 + kg * 4 + r);
      }
    int c_local = wc * 64 + fc * 16 + lr;
    scratch[slot * TC + c_local] =
        make_float4(t.v1, __int_as_float(t.i1), t.v2, __int_as_float(t.i2));
  }
  __syncthreads();

  if (tid < TC) {
    Top2 t; t.v1 = -1.f; t.v2 = -1.f; t.i1 = 0x7fffffff; t.i2 = 0x7fffffff;
#pragma unroll
    for (int s = 0; s < 8; s++) {
      float4 e = scratch[s * TC + tid];
      t2_insert(t, e.x, __float_as_int(e.y));
      t2_insert(t, e.z, __float_as_int(e.w));
    }
    int c = ct * TC + tid;
    size_t o = (((size_t)b * CC + c) * NPT + pt) * 3;
    uint32_t p1 = (uint32_t)(pt * TP + t.i1);
    uint32_t p2 = (uint32_t)(pt * TP + t.i2);
    // agent-scope (sc1) stores: visible at the device coherent point, no L2 flush
    __hip_atomic_store(&pw[o],     __float_as_uint(t.v1), __ATOMIC_RELAXED, __HIP_MEMORY_SCOPE_AGENT);
    __hip_atomic_store(&pw[o + 1], __float_as_uint(t.v2), __ATOMIC_RELAXED, __HIP_MEMORY_SCOPE_AGENT);
    __hip_atomic_store(&pw[o + 2], (p1 << 16) | (p2 & 0xffffu), __ATOMIC_RELAXED, __HIP_MEMORY_SCOPE_AGENT);
  }

  // ---- hand-rolled release: wait own stores complete, then bump counter
  MEMFENCE();
  __builtin_amdgcn_s_waitcnt(WAITCNT_VM0);
  MEMFENCE();
  if (tid == 0) lastflag = (atomicAdd(&cnt[b * 4 + ct], 1) == NPT - 1);
  __syncthreads();
  if (!lastflag) return;
  if (tid == 0) nf = 0;
  __syncthreads();

  if (tid < TC) {
    int c = ct * TC + tid;
    size_t base = (((size_t)b * CC + c) * NPT) * 3;
    Top2 g; g.v1 = -1.f; g.v2 = -1.f; g.i1 = 0x7fffffff; g.i2 = 0x7fffffff;
    for (int i = 0; i < NPT; i++) {
      float v1 = __uint_as_float(__hip_atomic_load(&pw[base + i * 3],     __ATOMIC_RELAXED, __HIP_MEMORY_SCOPE_AGENT));
      float v2 = __uint_as_float(__hip_atomic_load(&pw[base + i * 3 + 1], __ATOMIC_RELAXED, __HIP_MEMORY_SCOPE_AGENT));
      uint32_t ii =               __hip_atomic_load(&pw[base + i * 3 + 2], __ATOMIC_RELAXED, __HIP_MEMORY_SCOPE_AGENT);
      t2_insert(g, v1, (int)(ii >> 16));
      t2_insert(g, v2, (int)(ii & 0xffffu));
    }
    if (g.v1 - g.v2 > BAND) {
      win[b * CC + c] = g.i1;          // certain winner
    } else {
      int idx = atomicAdd(&nf, 1);     // rare: needs exact rescue
      flist[idx] = (short)tid;
    }
  }
  __syncthreads();

  // rescue flagged channels: exact fp64 dots over the certified candidate set
  for (int f = wave; f < nf; f += 4) {
    int c = ct * TC + flist[f];
    size_t base = (((size_t)b * CC + c) * NPT) * 3;
    float v1t = -1.f, v2t = -1.f; int i1t = 0, i2t = 0;
    if (lane < NPT) {
      v1t = __uint_as_float(__hip_atomic_load(&pw[base + lane * 3],     __ATOMIC_RELAXED, __HIP_MEMORY_SCOPE_AGENT));
      v2t = __uint_as_float(__hip_atomic_load(&pw[base + lane * 3 + 1], __ATOMIC_RELAXED, __HIP_MEMORY_SCOPE_AGENT));
      uint32_t ii =          __hip_atomic_load(&pw[base + lane * 3 + 2], __ATOMIC_RELAXED, __HIP_MEMORY_SCOPE_AGENT);
      i1t = (int)(ii >> 16); i2t = (int)(ii & 0xffffu);
    }
    float gv = v1t;
#pragma unroll
    for (int m = 1; m < 64; m <<= 1) gv = fmaxf(gv, __shfl_xor(gv, m, 64));
    float thr = gv - BAND;
    unsigned long long m1 = __ballot(lane < NPT && v1t >= thr);
    unsigned long long m2 = __ballot(lane < NPT && v2t >= thr);

    const float* xb = x + (size_t)b * PN * DD;
    const float* kr = kern + (size_t)c * DD;
    double bv = 0.0; int bp_ = 0;   // ties at <=0 resolve to argmax 0

    unsigned long long mm = m1;
    while (mm) {
      int sl_ = __ffsll((long long)mm) - 1; mm &= mm - 1;
      int p = __shfl(i1t, sl_, 64);
      double s = dot64(xb + (size_t)p * DD, kr, lane);
      if (s > bv || (s == bv && p < bp_)) { bv = s; bp_ = p; }
    }
    mm = m2;
    while (mm) {
      int sl_ = __ffsll((long long)mm) - 1; mm &= mm - 1;
      int p = __shfl(i2t, sl_, 64);
      double s = dot64(xb + (size_t)p * DD, kr, lane);
      if (s > bv || (s == bv && p < bp_)) { bv = s; bp_ = p; }
    }
    // deep tiles (tile_v2 >= thr): 3rd-best could hide -> scan whole tile
    mm = m2;
    while (mm) {
      int tl = __ffsll((long long)mm) - 1; mm &= mm - 1;
      const float* xA = xb + (size_t)(tl * TP + lane) * DD;
      const float* xB = xA + (size_t)64 * DD;
      double sA = 0.0, sB = 0.0;
      for (int i = 0; i < DD; i++) {
        double kv = (double)kr[i];
        sA += (double)xA[i] * kv;
        sB += (double)xB[i] * kv;
      }
      double lv = sA; int lp = tl * TP + lane;
      if (sB > lv) { lv = sB; lp = tl * TP + lane + 64; }
#pragma unroll
      for (int m = 1; m < 64; m <<= 1) {
        double ov = __shfl_xor(lv, m, 64);
        int    op = __shfl_xor(lp, m, 64);
        if (ov > lv || (ov == lv && op < lp)) { lv = ov; lp = op; }
      }
      if (lv > bv || (lv == bv && lp < bp_)) { bv = lv; bp_ = lp; }
    }
    if (bv <= 0.0) bp_ = 0;          // entire column relu'd to 0 -> argmax 0
    if (lane == 0) win[b * CC + c] = bp_;
  }
}

// ---------------------------------------------------------------------------
// 16 positions per block (4 waves x 4); winner row staged in LDS once.
// Ascending-channel add order. Full coverage -> no memset, no atomics.
// ---------------------------------------------------------------------------
__global__ __launch_bounds__(256) void write_out_kernel(
    const int* __restrict__ winner, const float* __restrict__ kern,
    float4* __restrict__ out) {
  __shared__ __align__(16) int wrow[CC];
  const int b = blockIdx.y;
  const int tid = threadIdx.x, lane = tid & 63, w = tid >> 6;

  *(int2*)&wrow[tid * 2] = *(const int2*)&winner[(size_t)b * CC + tid * 2];
  __syncthreads();

  int wv[8];
#pragma unroll
  for (int j = 0; j < 8; j++) wv[j] = wrow[j * 64 + lane];

#pragma unroll
  for (int pi = 0; pi < 4; pi++) {
    const int p = blockIdx.x * 16 + w * 4 + pi;
    float4 acc = make_float4(0.f, 0.f, 0.f, 0.f);
#pragma unroll
    for (int j = 0; j < 8; j++) {                 // j major: c ascending
      unsigned long long m = __ballot(wv[j] == p);
      while (m) {
        int bit = __ffsll((long long)m) - 1; m &= m - 1;
        int c = j * 64 + bit;                     // wave-uniform, ascending
        float4 kv = ((const float4*)(kern + (size_t)c * DD))[lane];
        acc.x += kv.x; acc.y += kv.y; acc.z += kv.z; acc.w += kv.w;
      }
    }
    out[((size_t)b * PN + p) * 64 + lane] = acc;
  }
}

// ---------------------------------------------------------------------------
extern "C" void kernel_launch(void* const* d_in, const int* in_sizes, int n_in,
                              void* d_out, int out_size, void* d_ws, size_t ws_size,
                              hipStream_t stream) {
  const float* x    = (const float*)d_in[0];   // (16,4096,256)
  const float* kern = (const float*)d_in[1];   // (512,256)
  float* out = (float*)d_out;

  // xh (fp16 slot-ordered x, 33.5 MB) lives in d_out; consumed by score,
  // then fully overwritten by write_out.
  uint32_t* xh = (uint32_t*)d_out;

  // ws: pw 3 MB | ks 512 KB | win 32 KB | cnt 256 B
  char* ws = (char*)d_ws;
  uint32_t* pw  = (uint32_t*)ws;
  uint32_t* ks  = (uint32_t*)(ws + 3u * 1024 * 1024);
  int*      win = (int*)(ws + 3u * 1024 * 1024 + 512u * 1024);
  int*      cnt = (int*)(ws + 3u * 1024 * 1024 + 512u * 1024 + 32u * 1024);

  prep_kernel<<<544, 256, 0, stream>>>(x, kern, xh, ks, cnt);

  score_kernel<<<dim3(CC / TC, NPT, BSZ), 256, 0, stream>>>(
      xh, ks, x, kern, pw, win, cnt);

  write_out_kernel<<<dim3(PN / 16, BSZ), 256, 0, stream>>>(win, kern, (float4*)out);
}

// Round 10
// 202.185 us; speedup vs baseline: 2.1746x; 1.1091x over previous
//
#include <hip/hip_runtime.h>
#include <hip/hip_fp16.h>
#include <cstddef>
#include <cstdint>

// x (16,4096,256) fp32, kernels (512,256) fp32, out (16,4096,256) fp32
#define BSZ 16
#define PN  4096
#define DD  256
#define CC  512
#define TP  128
#define TC  128
#define NPT (PN / TP)    // 32 position tiles
#define NKC 8            // 8 K-chunks of 32
#define KSCALE 1024.0f   // kernel pre-scale keeps fp16 splits normal-range
#define BAND 0.30f       // > 2 * rigorous score-error bound (scaled units)

typedef _Float16 f16x8 __attribute__((ext_vector_type(8)));
typedef float    f32x4 __attribute__((ext_vector_type(4)));

struct Top2 { float v1, v2; int i1, i2; };

// larger value wins; tie -> smaller index (jnp.argmax first-occurrence)
__device__ __forceinline__ void t2_insert(Top2& t, float v, int i) {
  if (v > t.v1 || (v == t.v1 && i < t.i1)) {
    t.v2 = t.v1; t.i2 = t.i1; t.v1 = v; t.i1 = i;
  } else if (v > t.v2 || (v == t.v2 && i < t.i2)) {
    t.v2 = v; t.i2 = i;
  }
}

// 8 fp32 -> 8 fp16 (RTN)
__device__ __forceinline__ f16x8 cvt8(float4 a, float4 b) {
  f16x8 r;
  r[0] = (_Float16)a.x; r[1] = (_Float16)a.y;
  r[2] = (_Float16)a.z; r[3] = (_Float16)a.w;
  r[4] = (_Float16)b.x; r[5] = (_Float16)b.y;
  r[6] = (_Float16)b.z; r[7] = (_Float16)b.w;
  return r;
}

// async 16B global -> LDS (dest = wave-uniform base + lane*16)
__device__ __forceinline__ void gld16(const void* gsrc, void* ldst) {
  __builtin_amdgcn_global_load_lds(
      (const __attribute__((address_space(1))) unsigned int*)gsrc,
      (__attribute__((address_space(3))) unsigned int*)ldst, 16, 0, 0);
}

// full-wave fp64 dot of one x row with one kernel row (all lanes get sum)
__device__ __forceinline__ double dot64(const float* __restrict__ xr,
                                        const float* __restrict__ kr, int lane) {
  int o = lane * 4;
  double s = (double)xr[o] * (double)kr[o]
           + (double)xr[o + 1] * (double)kr[o + 1]
           + (double)xr[o + 2] * (double)kr[o + 2]
           + (double)xr[o + 3] * (double)kr[o + 3];
#pragma unroll
  for (int m = 1; m < 64; m <<= 1) s += __shfl_xor(s, m, 64);
  return s;
}

// ---------------------------------------------------------------------------
// Prep (one dispatch, 544 blocks):
//   blocks 0..511  : x -> fp16 (RTN) in A-slot order -> xh (in d_out, 33.5 MB)
//                    chunk (b,pt,kc) = 8 KB, slot s = wr*256+fp*64+kg*16+lr
//                    holds row wr*64+fp*16+lr, k = kc*32+kg*8..+8.
//   blocks 512..543: kernels*KSCALE -> fp16 hi/lo in B-slot order -> ks
//                    chunk (ct,kc) = 16 KB [hi 8K | lo 8K].
// ---------------------------------------------------------------------------
__global__ __launch_bounds__(256) void prep_kernel(
    const float* __restrict__ x, const float* __restrict__ kern,
    uint32_t* __restrict__ xh, uint32_t* __restrict__ ks) {
  const int bid = blockIdx.x, tid = threadIdx.x;
  if (bid < 512) {
    const int b = bid >> 5, pt = bid & 31;
    const int r = tid >> 1, hh = tid & 1;
    const int wr = r >> 6, fp = (r >> 4) & 3, lr = r & 15;
    const float* src = x + ((size_t)(b * PN + pt * TP + r)) * DD + hh * 128;
    const size_t chunk0 = ((size_t)(b * NPT + pt) * NKC) * 2048;   // u32 units
#pragma unroll
    for (int g = 0; g < 16; g++) {
      int kc = hh * 4 + (g >> 2), kg = g & 3;
      float4 v0 = *(const float4*)(src + g * 8);
      float4 v1 = *(const float4*)(src + g * 8 + 4);
      f16x8 h = cvt8(v0, v1);
      int slot = wr * 256 + fp * 64 + kg * 16 + lr;
      *(uint4*)&xh[chunk0 + (size_t)kc * 2048 + (size_t)slot * 4] = *(uint4*)&h;
    }
  } else {
    const int kk = bid - 512;
    const int ct = kk >> 3, kc = kk & 7;
    const size_t chunk = ((size_t)(ct * NKC + kc)) * 4096;          // u32 units
#pragma unroll
    for (int s0 = 0; s0 < 2; s0++) {
      int s2 = tid + s0 * 256;
      int wc = s2 >> 8, fc = (s2 >> 6) & 3, kg = (s2 >> 4) & 3, lr = s2 & 15;
      int row = ct * TC + wc * 64 + fc * 16 + lr;
      const float* src = kern + (size_t)row * DD + kc * 32 + kg * 8;
      float4 v0 = *(const float4*)src, v1 = *(const float4*)(src + 4);
      float sv[8] = {v0.x, v0.y, v0.z, v0.w, v1.x, v1.y, v1.z, v1.w};
      f16x8 hi, lo;
#pragma unroll
      for (int i = 0; i < 8; i++) {
        float sc = sv[i] * KSCALE;
        _Float16 h = (_Float16)sc;
        hi[i] = h;
        lo[i] = (_Float16)(sc - (float)h);
      }
      *(uint4*)&ks[chunk + (size_t)s2 * 4]        = *(uint4*)&hi;
      *(uint4*)&ks[chunk + 2048 + (size_t)s2 * 4] = *(uint4*)&lo;
    }
  }
}

// ---------------------------------------------------------------------------
// Score GEMM: 128p x 128c per block, fp16 2-term (xh*kh + xh*kl), fused
// per-column top-2 over the p-tile. Contiguous gld16 staging, 24 KB/chunk,
// single-buffer 2-barrier loop. Block-id swizzle: the 4 ct-blocks of one
// (b,pt) sit 8 apart in linear id -> same XCD under round-robin dispatch
// -> A re-reads hit that XCD's L2.
// ---------------------------------------------------------------------------
__global__ __launch_bounds__(256) void score_kernel(
    const uint32_t* __restrict__ xh, const uint32_t* __restrict__ ks,
    float2* __restrict__ pv2, uint32_t* __restrict__ pix) {

  __shared__ __align__(16) char lds[24576];  // A f16 [0,8K) | B hi [8K,16K) | B lo [16K,24K)

  const int id = blockIdx.x;
  const int ct = (id >> 3) & 3;
  const int pb = ((id >> 5) << 3) | (id & 7);  // 0..511
  const int pt = pb & 31;
  const int b  = pb >> 5;

  const int tid  = threadIdx.x;
  const int lane = tid & 63, wave = tid >> 6;
  const int wr = wave >> 1, wc = wave & 1;
  const int lr = lane & 15, kg = lane >> 4;

  const char* asrc = (const char*)xh + ((size_t)(b * NPT + pt) * NKC) * 8192 + tid * 16;
  const char* bsrc = (const char*)ks + ((size_t)ct * NKC) * 16384 + tid * 16;

  f32x4 acc[4][4];
#pragma unroll
  for (int i = 0; i < 4; i++)
#pragma unroll
    for (int j = 0; j < 4; j++) acc[i][j] = (f32x4)0.f;

  for (int kc = 0; kc < NKC; kc++) {
#pragma unroll
    for (int i = 0; i < 2; i++)
      gld16(asrc + kc * 8192 + i * 4096, lds + i * 4096 + tid * 16);
#pragma unroll
    for (int i = 0; i < 4; i++)
      gld16(bsrc + kc * 16384 + i * 4096, lds + 8192 + i * 4096 + tid * 16);
    __syncthreads();   // drains vmcnt -> staged data visible

    f16x8 Ah[4];
#pragma unroll
    for (int fp = 0; fp < 4; fp++)
      Ah[fp] = *(const f16x8*)(lds + wr * 4096 + fp * 1024 + lane * 16);
#pragma unroll
    for (int fc = 0; fc < 4; fc++) {
      const char* bp = lds + 8192 + wc * 4096 + fc * 1024 + lane * 16;
      f16x8 Bh = *(const f16x8*)bp;
      f16x8 Bl = *(const f16x8*)(bp + 8192);
#pragma unroll
      for (int fp = 0; fp < 4; fp++) {
        acc[fp][fc] = __builtin_amdgcn_mfma_f32_16x16x32_f16(Ah[fp], Bh, acc[fp][fc], 0, 0, 0);
        acc[fp][fc] = __builtin_amdgcn_mfma_f32_16x16x32_f16(Ah[fp], Bl, acc[fp][fc], 0, 0, 0);
      }
    }
    __syncthreads();   // frag reads done before next chunk overwrites LDS
  }

  // relu + per-lane top2 per column (C layout: col=lane&15, row=kg*4+reg)
  float4* scratch = (float4*)lds;   // reuse tile LDS: [slot 0..7][col 0..127]
  const int slot = wr * 4 + kg;
#pragma unroll
  for (int fc = 0; fc < 4; fc++) {
    Top2 t; t.v1 = -1.f; t.v2 = -1.f; t.i1 = 0x7fffffff; t.i2 = 0x7fffffff;
#pragma unroll
    for (int fp = 0; fp < 4; fp++)
#pragma unroll
      for (int r = 0; r < 4; r++) {
        float v = acc[fp][fc][r]; v = v > 0.f ? v : 0.f;
        t2_insert(t, v, wr * 64 + fp * 16 + kg * 4 + r);
      }
    int c_local = wc * 64 + fc * 16 + lr;
    scratch[slot * TC + c_local] =
        make_float4(t.v1, __int_as_float(t.i1), t.v2, __int_as_float(t.i2));
  }
  __syncthreads();

  if (tid < TC) {
    Top2 t; t.v1 = -1.f; t.v2 = -1.f; t.i1 = 0x7fffffff; t.i2 = 0x7fffffff;
#pragma unroll
    for (int s = 0; s < 8; s++) {
      float4 e = scratch[s * TC + tid];
      t2_insert(t, e.x, __float_as_int(e.y));
      t2_insert(t, e.z, __float_as_int(e.w));
    }
    int c = ct * TC + tid;
    size_t o = ((size_t)b * CC + c) * NPT + pt;
    uint32_t p1 = (uint32_t)(pt * TP + t.i1);
    uint32_t p2 = (uint32_t)(pt * TP + t.i2);
    pv2[o] = make_float2(t.v1, t.v2);
    pix[o] = (p1 << 16) | (p2 & 0xffffu);
  }
}

// ---------------------------------------------------------------------------
// Reduce: one wave per (b,c). Merge 32 tile top-2s; if the gap exceeds BAND
// the approx winner is certain; else exact fp64 rescue over the certified
// candidate set (tile winners >= thr, plus full scan of deep tiles).
// ---------------------------------------------------------------------------
__global__ __launch_bounds__(256) void reduce_winner_kernel(
    const float2* __restrict__ pv2, const uint32_t* __restrict__ pix,
    const float* __restrict__ x, const float* __restrict__ kern,
    int* __restrict__ win) {
  const int c = blockIdx.x * 4 + (threadIdx.x >> 6);
  const int b = blockIdx.y;
  const int lane = threadIdx.x & 63;

  float v1t = -1.f, v2t = -1.f; int i1t = 0x7fffffff, i2t = 0x7fffffff;
  if (lane < NPT) {
    size_t o = ((size_t)b * CC + c) * NPT + lane;
    float2 v = pv2[o]; uint32_t ii = pix[o];
    v1t = v.x; v2t = v.y; i1t = (int)(ii >> 16); i2t = (int)(ii & 0xffffu);
  }
  Top2 g; g.v1 = v1t; g.v2 = v2t; g.i1 = i1t; g.i2 = i2t;
#pragma unroll
  for (int m = 1; m < 64; m <<= 1) {
    float uv1 = __shfl_xor(g.v1, m, 64);
    int   ui1 = __shfl_xor(g.i1, m, 64);
    float uv2 = __shfl_xor(g.v2, m, 64);
    int   ui2 = __shfl_xor(g.i2, m, 64);
    t2_insert(g, uv1, ui1);
    t2_insert(g, uv2, ui2);
  }

  if (g.v1 - g.v2 > BAND) {
    if (lane == 0) win[b * CC + c] = g.i1;
    return;
  }

  // rescue: exact fp64 dots over the certified candidate set
  float thr = g.v1 - BAND;
  unsigned long long m1 = __ballot(lane < NPT && v1t >= thr);
  unsigned long long m2 = __ballot(lane < NPT && v2t >= thr);

  const float* xb = x + (size_t)b * PN * DD;
  const float* kr = kern + (size_t)c * DD;
  double bv = 0.0; int bp_ = 0;   // ties at <=0 resolve to argmax 0

  unsigned long long mm = m1;
  while (mm) {
    int sl_ = __ffsll((long long)mm) - 1; mm &= mm - 1;
    int p = __shfl(i1t, sl_, 64);
    double s = dot64(xb + (size_t)p * DD, kr, lane);
    if (s > bv || (s == bv && p < bp_)) { bv = s; bp_ = p; }
  }
  mm = m2;
  while (mm) {
    int sl_ = __ffsll((long long)mm) - 1; mm &= mm - 1;
    int p = __shfl(i2t, sl_, 64);
    double s = dot64(xb + (size_t)p * DD, kr, lane);
    if (s > bv || (s == bv && p < bp_)) { bv = s; bp_ = p; }
  }
  // deep tiles (tile_v2 >= thr): 3rd-best could hide -> scan whole tile
  mm = m2;
  while (mm) {
    int tl = __ffsll((long long)mm) - 1; mm &= mm - 1;
    const float* xA = xb + (size_t)(tl * TP + lane) * DD;
    const float* xB = xA + (size_t)64 * DD;
    double sA = 0.0, sB = 0.0;
    for (int i = 0; i < DD; i++) {
      double kv = (double)kr[i];
      sA += (double)xA[i] * kv;
      sB += (double)xB[i] * kv;
    }
    double lv = sA; int lp = tl * TP + lane;
    if (sB > lv) { lv = sB; lp = tl * TP + lane + 64; }
#pragma unroll
    for (int m = 1; m < 64; m <<= 1) {
      double ov = __shfl_xor(lv, m, 64);
      int    op = __shfl_xor(lp, m, 64);
      if (ov > lv || (ov == lv && op < lp)) { lv = ov; lp = op; }
    }
    if (lv > bv || (lv == bv && lp < bp_)) { bv = lv; bp_ = lp; }
  }
  if (bv <= 0.0) bp_ = 0;          // entire column relu'd to 0 -> argmax 0
  if (lane == 0) win[b * CC + c] = bp_;
}

// ---------------------------------------------------------------------------
// 16 positions per block (4 waves x 4); winner row staged in LDS once.
// Ascending-channel add order. Full coverage -> no memset, no atomics.
// ---------------------------------------------------------------------------
__global__ __launch_bounds__(256) void write_out_kernel(
    const int* __restrict__ winner, const float* __restrict__ kern,
    float4* __restrict__ out) {
  __shared__ __align__(16) int wrow[CC];
  const int b = blockIdx.y;
  const int tid = threadIdx.x, lane = tid & 63, w = tid >> 6;

  *(int2*)&wrow[tid * 2] = *(const int2*)&winner[(size_t)b * CC + tid * 2];
  __syncthreads();

  int wv[8];
#pragma unroll
  for (int j = 0; j < 8; j++) wv[j] = wrow[j * 64 + lane];

#pragma unroll
  for (int pi = 0; pi < 4; pi++) {
    const int p = blockIdx.x * 16 + w * 4 + pi;
    float4 acc = make_float4(0.f, 0.f, 0.f, 0.f);
#pragma unroll
    for (int j = 0; j < 8; j++) {                 // j major: c ascending
      unsigned long long m = __ballot(wv[j] == p);
      while (m) {
        int bit = __ffsll((long long)m) - 1; m &= m - 1;
        int c = j * 64 + bit;                     // wave-uniform, ascending
        float4 kv = ((const float4*)(kern + (size_t)c * DD))[lane];
        acc.x += kv.x; acc.y += kv.y; acc.z += kv.z; acc.w += kv.w;
      }
    }
    out[((size_t)b * PN + p) * 64 + lane] = acc;
  }
}

// ---------------------------------------------------------------------------
extern "C" void kernel_launch(void* const* d_in, const int* in_sizes, int n_in,
                              void* d_out, int out_size, void* d_ws, size_t ws_size,
                              hipStream_t stream) {
  const float* x    = (const float*)d_in[0];   // (16,4096,256)
  const float* kern = (const float*)d_in[1];   // (512,256)
  float* out = (float*)d_out;

  // xh (fp16 slot-ordered x, 33.5 MB) lives in d_out; consumed by score,
  // then fully overwritten by write_out.
  uint32_t* xh = (uint32_t*)d_out;

  // ws: pv2 2 MB | pix 1 MB | ks 512 KB | win 32 KB
  char* ws = (char*)d_ws;
  float2*   pv2 = (float2*)ws;
  uint32_t* pix = (uint32_t*)(ws + 2u * 1024 * 1024);
  uint32_t* ks  = (uint32_t*)(ws + 3u * 1024 * 1024);
  int*      win = (int*)(ws + 3u * 1024 * 1024 + 512u * 1024);

  prep_kernel<<<544, 256, 0, stream>>>(x, kern, xh, ks);

  score_kernel<<<dim3(4 * NPT * BSZ), 256, 0, stream>>>(xh, ks, pv2, pix);

  reduce_winner_kernel<<<dim3(CC / 4, BSZ), 256, 0, stream>>>(pv2, pix, x, kern, win);

  write_out_kernel<<<dim3(PN / 16, BSZ), 256, 0, stream>>>(win, kern, (float4*)out);
}